// Round 1
// 1995.104 us; speedup vs baseline: 1.0400x; 1.0400x over previous
//
#include <hip/hip_runtime.h>
#include <hip/hip_bf16.h>

// MultiheadDiffAttn on MI355X.
// Pipeline: cast f32->bf16 -> 3x MFMA GEMM (Q,K cat-proj; V proj stored transposed)
//        -> fused diff-attention (QK^T, softmax x2, att write (output 1), PV, RMSNorm)
//        -> MFMA GEMM out-projection (output 0).
// Workspace usage ~192 MiB.
// R1: diff_attn traffic fixes: XCD-concentrating swizzle (K/V L2 reuse),
//     LDS-staged coalesced nontemporal fp32 att writes, staged bf16x8 Y writes.

typedef __bf16 bf16x8 __attribute__((ext_vector_type(8)));
typedef float f32x4 __attribute__((ext_vector_type(4)));

#define MFMA16(a, b, c) __builtin_amdgcn_mfma_f32_16x16x32_bf16(a, b, c, 0, 0, 0)

__global__ __launch_bounds__(256) void cast_f32_to_bf16_k(const float* __restrict__ src,
                                                          __bf16* __restrict__ dst, int n8) {
  int i = blockIdx.x * 256 + threadIdx.x;
  if (i < n8) {
    const float4* s = (const float4*)src;
    float4 f0 = s[i * 2], f1 = s[i * 2 + 1];
    bf16x8 o;
    o[0] = (__bf16)f0.x; o[1] = (__bf16)f0.y; o[2] = (__bf16)f0.z; o[3] = (__bf16)f0.w;
    o[4] = (__bf16)f1.x; o[5] = (__bf16)f1.y; o[6] = (__bf16)f1.z; o[7] = (__bf16)f1.w;
    ((bf16x8*)dst)[i] = o;
  }
}

// C[m][n] = sum_k A[m][k] * B[n][k]  (B is [N][K] row-major = weights for x@W.T)
// MODE 0: A rows map m=(b,s) from [S,B,E] input; C bf16 at m*2048+n      (Q/K proj)
// MODE 1: same A; C bf16 stored transposed: [(b*2048+n)*1024 + s]        (V proj -> VT)
// MODE 2: A = Y ws [B,H,S,128] with m=(s,b), k=h*128+d; C fp32 m*1024+n  (out proj)
template <int MODE>
__global__ __launch_bounds__(256) void gemm_mfma_k(const __bf16* __restrict__ A,
                                                   const __bf16* __restrict__ B,
                                                   void* __restrict__ Cout, int K) {
  const int m0 = blockIdx.x * 128;
  const int n0 = blockIdx.y * 128;
  const int tid = threadIdx.x;
  const int lane = tid & 63;
  const int w = tid >> 6;
  const int wm = (w >> 1) * 64;
  const int wn = (w & 1) * 64;
  const int l15 = lane & 15;
  const int quad = lane >> 4;

  __shared__ __align__(16) __bf16 As[4][128][8];  // [k-chunk][m][8] -> bank-balanced b128
  __shared__ __align__(16) __bf16 Bs[4][128][8];

  f32x4 acc[4][4] = {};

  for (int k0 = 0; k0 < K; k0 += 32) {
#pragma unroll
    for (int c0 = 0; c0 < 2; c0++) {
      int c = tid + c0 * 256;
      int ml = c >> 2, q = c & 3;
      long aoff;
      if constexpr (MODE == 2) {
        int m = m0 + ml;
        int s = m >> 3, b = m & 7;
        int k = k0 + q * 8;
        aoff = (long)((b * 16 + (k >> 7)) * 1024 + s) * 128 + (k & 127);
      } else {
        int m = m0 + ml;
        int s = m & 1023, b = m >> 10;
        aoff = (long)(s * 8 + b) * 1024 + k0 + q * 8;
      }
      *(bf16x8*)(&As[q][ml][0]) = *(const bf16x8*)(A + aoff);
      *(bf16x8*)(&Bs[q][ml][0]) = *(const bf16x8*)(B + (long)(n0 + ml) * K + k0 + q * 8);
    }
    __syncthreads();
    bf16x8 af[4], bfr[4];
#pragma unroll
    for (int i = 0; i < 4; i++) af[i] = *(const bf16x8*)(&As[quad][wm + i * 16 + l15][0]);
#pragma unroll
    for (int j = 0; j < 4; j++) bfr[j] = *(const bf16x8*)(&Bs[quad][wn + j * 16 + l15][0]);
#pragma unroll
    for (int i = 0; i < 4; i++)
#pragma unroll
      for (int j = 0; j < 4; j++) acc[i][j] = MFMA16(af[i], bfr[j], acc[i][j]);
    __syncthreads();
  }

#pragma unroll
  for (int i = 0; i < 4; i++) {
#pragma unroll
    for (int j = 0; j < 4; j++) {
#pragma unroll
      for (int r = 0; r < 4; r++) {
        int row = m0 + wm + i * 16 + quad * 4 + r;  // C/D: row=(lane>>4)*4+reg, col=lane&15
        int col = n0 + wn + j * 16 + l15;
        float v = acc[i][j][r];
        if constexpr (MODE == 0) {
          ((__bf16*)Cout)[(long)row * 2048 + col] = (__bf16)v;
        } else if constexpr (MODE == 1) {
          int b = row >> 10, s = row & 1023;
          ((__bf16*)Cout)[(long)(b * 2048 + col) * 1024 + s] = (__bf16)v;
        } else {
          ((float*)Cout)[(long)row * 1024 + col] = v;
        }
      }
    }
  }
}

// reduce v[r] across the 16-lane col group, then across 4 waves. OP 0=max, 1=sum.
template <int OP>
__device__ __forceinline__ void block_row_reduce(float v[4], float (*red)[16], int w, int quad,
                                                 int l15) {
#pragma unroll
  for (int r = 0; r < 4; r++) {
    float x = v[r];
#pragma unroll
    for (int m = 1; m < 16; m <<= 1) {
      float o = __shfl_xor(x, m, 64);
      x = OP ? (x + o) : fmaxf(x, o);
    }
    v[r] = x;
  }
  __syncthreads();
  if (l15 == 0) {
#pragma unroll
    for (int r = 0; r < 4; r++) red[w][quad * 4 + r] = v[r];
  }
  __syncthreads();
#pragma unroll
  for (int r = 0; r < 4; r++) {
    float x = red[0][quad * 4 + r];
#pragma unroll
    for (int ww = 1; ww < 4; ww++) {
      float o = red[ww][quad * 4 + r];
      x = OP ? (x + o) : fmaxf(x, o);
    }
    v[r] = x;
  }
}

// One block = (b, h, 16 q-rows). Scores for both attention maps kept in registers
// (2 x 16 tiles x f32x4). att round-trips LDS (bf16) for the PV A-operand relayout.
// Block swizzle: all 64 q-tiles of one (b,h) share bid%8 -> same XCD -> K/VT slices
// (512 KiB) stay resident in that XCD's 4 MiB L2.
__global__ __launch_bounds__(256) void diff_attn_k(
    const __bf16* __restrict__ Q, const __bf16* __restrict__ Km, const __bf16* __restrict__ VT,
    float* __restrict__ att_out, __bf16* __restrict__ Y, const float* __restrict__ lq1,
    const float* __restrict__ lk1, const float* __restrict__ lq2, const float* __restrict__ lk2,
    const float* __restrict__ rmsw) {
  const int bid = blockIdx.x;
  const int xcd = bid & 7;          // HW round-robins bid%8 across XCDs
  const int rest = bid >> 3;        // 0..1023
  const int qt = rest & 63;
  const int g = (rest >> 6) * 8 + xcd;  // group 0..127, constant per XCD-slot
  const int h = g & 15;
  const int b = g >> 4;
  const int q0 = qt * 16;
  const int tid = threadIdx.x;
  const int lane = tid & 63;
  const int w = tid >> 6;
  const int l15 = lane & 15;
  const int quad = lane >> 4;

  __shared__ __align__(16) __bf16 att_s[16][1032];  // +8 pad: 2064B stride, bank-balanced
  __shared__ __align__(16) float fstage[16][268];   // f32 att staging (also Y bf16 staging)
  __shared__ float red[4][16];
  __shared__ float s_lam;

  if (tid == 0) {
    float d1 = 0.f, d2 = 0.f;
    for (int i = 0; i < 64; i++) {
      d1 += lq1[i] * lk1[i];
      d2 += lq2[i] * lk2[i];
    }
    s_lam = __expf(d1) - __expf(d2) + 0.2f;  // lambda_full, LAMBDA_INIT=0.2
  }

  // A-frags for q1/q2 (M=16 rows, K=64 as 2 chunks of 32)
  const __bf16* qrow = Q + (long)(b * 1024 + q0 + l15) * 2048 + h * 64 + quad * 8;
  bf16x8 aq1[2], aq2[2];
  aq1[0] = *(const bf16x8*)(qrow);
  aq1[1] = *(const bf16x8*)(qrow + 32);
  aq2[0] = *(const bf16x8*)(qrow + 1024);
  aq2[1] = *(const bf16x8*)(qrow + 1056);

  f32x4 s1[16], s2[16];  // wave w covers key-cols [w*256, w*256+256)
  const __bf16* kb = Km + (long)(b * 1024) * 2048 + h * 64 + quad * 8;
#pragma unroll 4
  for (int t = 0; t < 16; t++) {
    const __bf16* kr = kb + (long)(w * 256 + t * 16 + l15) * 2048;
    bf16x8 b10 = *(const bf16x8*)(kr);
    bf16x8 b11 = *(const bf16x8*)(kr + 32);
    bf16x8 b20 = *(const bf16x8*)(kr + 1024);
    bf16x8 b21 = *(const bf16x8*)(kr + 1056);
    f32x4 a = {0.f, 0.f, 0.f, 0.f};
    a = MFMA16(aq1[0], b10, a);
    a = MFMA16(aq1[1], b11, a);
    s1[t] = a;
    f32x4 a2 = {0.f, 0.f, 0.f, 0.f};
    a2 = MFMA16(aq2[0], b20, a2);
    a2 = MFMA16(aq2[1], b21, a2);
    s2[t] = a2;
  }

  const float scale = 0.125f;  // Dh^-0.5
  float m1[4], m2[4];
#pragma unroll
  for (int r = 0; r < 4; r++) {
    float x1 = -3.4e38f, x2 = -3.4e38f;
#pragma unroll
    for (int t = 0; t < 16; t++) {
      x1 = fmaxf(x1, s1[t][r]);
      x2 = fmaxf(x2, s2[t][r]);
    }
    m1[r] = x1;
    m2[r] = x2;
  }
  block_row_reduce<0>(m1, red, w, quad, l15);
  block_row_reduce<0>(m2, red, w, quad, l15);

  float sum1[4] = {0.f, 0.f, 0.f, 0.f}, sum2[4] = {0.f, 0.f, 0.f, 0.f};
#pragma unroll
  for (int t = 0; t < 16; t++) {
#pragma unroll
    for (int r = 0; r < 4; r++) {
      float e1 = __expf((s1[t][r] - m1[r]) * scale);
      float e2 = __expf((s2[t][r] - m2[r]) * scale);
      s1[t][r] = e1;
      s2[t][r] = e2;
      sum1[r] += e1;
      sum2[r] += e2;
    }
  }
  block_row_reduce<1>(sum1, red, w, quad, l15);
  block_row_reduce<1>(sum2, red, w, quad, l15);

  const float lam = s_lam;
  float i1[4], i2[4];
#pragma unroll
  for (int r = 0; r < 4; r++) {
    i1[r] = 1.f / sum1[r];
    i2[r] = lam / sum2[r];
  }

  // bf16 att tile for PV A-operand relayout (unchanged)
#pragma unroll
  for (int t = 0; t < 16; t++) {
    int col = w * 256 + t * 16 + l15;
#pragma unroll
    for (int r = 0; r < 4; r++) {
      int row = quad * 4 + r;
      float av = s1[t][r] * i1[r] - s2[t][r] * i2[r];
      att_s[row][col] = (__bf16)av;
    }
  }
  __syncthreads();

  // fp32 att output (output 1): 4 per-wave staging passes -> fully-coalesced
  // 1 KiB/wave nontemporal dwordx4 stores (full 128B lines, no L2 pollution).
  float* abase = att_out + (long)((b * 16 + h) * 1024 + q0) * 1024;
#pragma unroll 1
  for (int p = 0; p < 4; p++) {
    if (w == p) {
#pragma unroll
      for (int t = 0; t < 16; t++) {
#pragma unroll
        for (int r = 0; r < 4; r++) {
          fstage[quad * 4 + r][t * 16 + l15] = s1[t][r] * i1[r] - s2[t][r] * i2[r];
        }
      }
    }
    __syncthreads();
#pragma unroll
    for (int j = 0; j < 4; j++) {
      int f = tid + j * 256;
      int row = f >> 6, c4 = f & 63;
      f32x4 v = *(const f32x4*)(&fstage[row][c4 * 4]);
      __builtin_nontemporal_store(v, (f32x4*)(abase + (long)row * 1024 + p * 256 + c4 * 4));
    }
    if (p < 3) __syncthreads();
  }

  // PV: y[16][128] = att[16][1024] @ v[1024][128]; wave w covers d in [w*32, w*32+32)
  f32x4 y0 = {0.f, 0.f, 0.f, 0.f}, y1 = {0.f, 0.f, 0.f, 0.f};
  const __bf16* vb = VT + (long)(b * 2048 + h * 128 + w * 32 + l15) * 1024 + quad * 8;
#pragma unroll 8
  for (int c = 0; c < 32; c++) {
    bf16x8 afr = *(const bf16x8*)(&att_s[l15][c * 32 + quad * 8]);
    bf16x8 b0 = *(const bf16x8*)(vb + c * 32);
    bf16x8 b1 = *(const bf16x8*)(vb + (long)16 * 1024 + c * 32);
    y0 = MFMA16(afr, b0, y0);
    y1 = MFMA16(afr, b1, y1);
  }

  // RMSNorm over d=128 + affine weight + (1 - lambda_init)=0.8
  float ss[4];
#pragma unroll
  for (int r = 0; r < 4; r++) ss[r] = y0[r] * y0[r] + y1[r] * y1[r];
  block_row_reduce<1>(ss, red, w, quad, l15);

  const int d0 = w * 32 + l15;
  const float rw0 = rmsw[d0], rw1 = rmsw[d0 + 16];
  // stage Y bf16 in LDS (reuse fstage memory; all fp32-pass reads completed inside
  // block_row_reduce's barriers), then write 256B-contiguous bf16x8 rows.
  __bf16* ystage = (__bf16*)fstage;  // [16][136] layout
#pragma unroll
  for (int r = 0; r < 4; r++) {
    float rinv = rsqrtf(ss[r] * (1.f / 128.f) + 1e-5f);
    int row = quad * 4 + r;
    ystage[row * 136 + d0] = (__bf16)(y0[r] * rinv * rw0 * 0.8f);
    ystage[row * 136 + d0 + 16] = (__bf16)(y1[r] * rinv * rw1 * 0.8f);
  }
  __syncthreads();
  {
    __bf16* ybase = Y + (long)((b * 16 + h) * 1024 + q0) * 128;
    int row = tid >> 4, c8 = tid & 15;
    bf16x8 v = *(const bf16x8*)(&ystage[row * 136 + c8 * 8]);
    *(bf16x8*)(ybase + row * 128 + c8 * 8) = v;
  }
}

extern "C" void kernel_launch(void* const* d_in, const int* in_sizes, int n_in, void* d_out,
                              int out_size, void* d_ws, size_t ws_size, hipStream_t stream) {
  const float* query = (const float*)d_in[0];
  const float* key = (const float*)d_in[1];
  const float* value = (const float*)d_in[2];
  const float* Wq1 = (const float*)d_in[3];
  const float* Wq2 = (const float*)d_in[4];
  const float* Wk1 = (const float*)d_in[5];
  const float* Wk2 = (const float*)d_in[6];
  const float* Wv = (const float*)d_in[7];
  const float* Wout = (const float*)d_in[8];
  const float* lq1 = (const float*)d_in[9];
  const float* lk1 = (const float*)d_in[10];
  const float* lq2 = (const float*)d_in[11];
  const float* lk2 = (const float*)d_in[12];
  const float* rmsw = (const float*)d_in[13];

  char* ws = (char*)d_ws;
  size_t off = 0;
  auto alloc = [&](size_t bytes) {
    void* p = ws + off;
    off += (bytes + 255) & ~255UL;
    return p;
  };
  const size_t SBE = 8388608;  // 1024*8*1024
  __bf16* qb16 = (__bf16*)alloc(SBE * 2);
  __bf16* kb16 = (__bf16*)alloc(SBE * 2);
  __bf16* vb16 = (__bf16*)alloc(SBE * 2);
  __bf16* wq = (__bf16*)alloc(2097152 * 2);    // [Wq1;Wq2] as [2048][1024]
  __bf16* wk = (__bf16*)alloc(2097152 * 2);
  __bf16* wv = (__bf16*)alloc(2097152 * 2);    // [2048][1024]
  __bf16* wout = (__bf16*)alloc(2097152 * 2);  // [1024][2048]
  __bf16* Qws = (__bf16*)alloc((size_t)8192 * 2048 * 2);
  __bf16* Kws = (__bf16*)alloc((size_t)8192 * 2048 * 2);
  __bf16* VTws = (__bf16*)alloc((size_t)8192 * 2048 * 2);
  __bf16* Yws = (__bf16*)alloc((size_t)8192 * 2048 * 2);

  auto cast = [&](const float* s, __bf16* d, size_t n) {
    int n8 = (int)(n / 8);
    cast_f32_to_bf16_k<<<(n8 + 255) / 256, 256, 0, stream>>>(s, d, n8);
  };
  cast(query, qb16, SBE);
  cast(key, kb16, SBE);
  cast(value, vb16, SBE);
  cast(Wq1, wq, 1048576);
  cast(Wq2, wq + 1048576, 1048576);
  cast(Wk1, wk, 1048576);
  cast(Wk2, wk + 1048576, 1048576);
  cast(Wv, wv, 2097152);
  cast(Wout, wout, 2097152);

  gemm_mfma_k<0><<<dim3(64, 16), 256, 0, stream>>>(qb16, wq, Qws, 1024);
  gemm_mfma_k<0><<<dim3(64, 16), 256, 0, stream>>>(kb16, wk, Kws, 1024);
  gemm_mfma_k<1><<<dim3(64, 16), 256, 0, stream>>>(vb16, wv, VTws, 1024);

  float* att_out = (float*)d_out + SBE;
  diff_attn_k<<<8192, 256, 0, stream>>>(Qws, Kws, VTws, att_out, Yws, lq1, lk1, lq2, lk2, rmsw);

  gemm_mfma_k<2><<<dim3(64, 8), 256, 0, stream>>>(Yws, wout, (float*)d_out, 2048);
}

// Round 2
// 1302.219 us; speedup vs baseline: 1.5934x; 1.5321x over previous
//
#include <hip/hip_runtime.h>
#include <hip/hip_bf16.h>

// MultiheadDiffAttn on MI355X.
// Pipeline: cast f32->bf16 -> 3x MFMA GEMM (Q,K cat-proj; V proj stored transposed)
//        -> fused diff-attention (QK^T, softmax x2, att write (output 1), PV, RMSNorm)
//        -> MFMA GEMM out-projection (output 0).
// Workspace usage ~192 MiB.
// R1: XCD-concentrating swizzle (K/V L2 reuse) - kept (FETCH 1.75->1.29 GB).
// R2: kill scratch spills: score arrays s1/s2 (128 f32/thread) were runtime-indexed
//     (QK loop was unroll-4) -> local memory -> ~3 GB hidden scratch traffic.
//     Full unroll + __launch_bounds__(256,2) keeps scores in VGPRs.
//     Reverted LDS store-staging (measured zero WRITE_SIZE effect).

typedef __bf16 bf16x8 __attribute__((ext_vector_type(8)));
typedef float f32x4 __attribute__((ext_vector_type(4)));

#define MFMA16(a, b, c) __builtin_amdgcn_mfma_f32_16x16x32_bf16(a, b, c, 0, 0, 0)

__global__ __launch_bounds__(256) void cast_f32_to_bf16_k(const float* __restrict__ src,
                                                          __bf16* __restrict__ dst, int n8) {
  int i = blockIdx.x * 256 + threadIdx.x;
  if (i < n8) {
    const float4* s = (const float4*)src;
    float4 f0 = s[i * 2], f1 = s[i * 2 + 1];
    bf16x8 o;
    o[0] = (__bf16)f0.x; o[1] = (__bf16)f0.y; o[2] = (__bf16)f0.z; o[3] = (__bf16)f0.w;
    o[4] = (__bf16)f1.x; o[5] = (__bf16)f1.y; o[6] = (__bf16)f1.z; o[7] = (__bf16)f1.w;
    ((bf16x8*)dst)[i] = o;
  }
}

// C[m][n] = sum_k A[m][k] * B[n][k]  (B is [N][K] row-major = weights for x@W.T)
// MODE 0: A rows map m=(b,s) from [S,B,E] input; C bf16 at m*2048+n      (Q/K proj)
// MODE 1: same A; C bf16 stored transposed: [(b*2048+n)*1024 + s]        (V proj -> VT)
// MODE 2: A = Y ws [B,H,S,128] with m=(s,b), k=h*128+d; C fp32 m*1024+n  (out proj)
template <int MODE>
__global__ __launch_bounds__(256) void gemm_mfma_k(const __bf16* __restrict__ A,
                                                   const __bf16* __restrict__ B,
                                                   void* __restrict__ Cout, int K) {
  const int m0 = blockIdx.x * 128;
  const int n0 = blockIdx.y * 128;
  const int tid = threadIdx.x;
  const int lane = tid & 63;
  const int w = tid >> 6;
  const int wm = (w >> 1) * 64;
  const int wn = (w & 1) * 64;
  const int l15 = lane & 15;
  const int quad = lane >> 4;

  __shared__ __align__(16) __bf16 As[4][128][8];  // [k-chunk][m][8] -> bank-balanced b128
  __shared__ __align__(16) __bf16 Bs[4][128][8];

  f32x4 acc[4][4] = {};

  for (int k0 = 0; k0 < K; k0 += 32) {
#pragma unroll
    for (int c0 = 0; c0 < 2; c0++) {
      int c = tid + c0 * 256;
      int ml = c >> 2, q = c & 3;
      long aoff;
      if constexpr (MODE == 2) {
        int m = m0 + ml;
        int s = m >> 3, b = m & 7;
        int k = k0 + q * 8;
        aoff = (long)((b * 16 + (k >> 7)) * 1024 + s) * 128 + (k & 127);
      } else {
        int m = m0 + ml;
        int s = m & 1023, b = m >> 10;
        aoff = (long)(s * 8 + b) * 1024 + k0 + q * 8;
      }
      *(bf16x8*)(&As[q][ml][0]) = *(const bf16x8*)(A + aoff);
      *(bf16x8*)(&Bs[q][ml][0]) = *(const bf16x8*)(B + (long)(n0 + ml) * K + k0 + q * 8);
    }
    __syncthreads();
    bf16x8 af[4], bfr[4];
#pragma unroll
    for (int i = 0; i < 4; i++) af[i] = *(const bf16x8*)(&As[quad][wm + i * 16 + l15][0]);
#pragma unroll
    for (int j = 0; j < 4; j++) bfr[j] = *(const bf16x8*)(&Bs[quad][wn + j * 16 + l15][0]);
#pragma unroll
    for (int i = 0; i < 4; i++)
#pragma unroll
      for (int j = 0; j < 4; j++) acc[i][j] = MFMA16(af[i], bfr[j], acc[i][j]);
    __syncthreads();
  }

#pragma unroll
  for (int i = 0; i < 4; i++) {
#pragma unroll
    for (int j = 0; j < 4; j++) {
#pragma unroll
      for (int r = 0; r < 4; r++) {
        int row = m0 + wm + i * 16 + quad * 4 + r;  // C/D: row=(lane>>4)*4+reg, col=lane&15
        int col = n0 + wn + j * 16 + l15;
        float v = acc[i][j][r];
        if constexpr (MODE == 0) {
          ((__bf16*)Cout)[(long)row * 2048 + col] = (__bf16)v;
        } else if constexpr (MODE == 1) {
          int b = row >> 10, s = row & 1023;
          ((__bf16*)Cout)[(long)(b * 2048 + col) * 1024 + s] = (__bf16)v;
        } else {
          ((float*)Cout)[(long)row * 1024 + col] = v;
        }
      }
    }
  }
}

// reduce v[r] across the 16-lane col group, then across 4 waves. OP 0=max, 1=sum.
template <int OP>
__device__ __forceinline__ void block_row_reduce(float v[4], float (*red)[16], int w, int quad,
                                                 int l15) {
#pragma unroll
  for (int r = 0; r < 4; r++) {
    float x = v[r];
#pragma unroll
    for (int m = 1; m < 16; m <<= 1) {
      float o = __shfl_xor(x, m, 64);
      x = OP ? (x + o) : fmaxf(x, o);
    }
    v[r] = x;
  }
  __syncthreads();
  if (l15 == 0) {
#pragma unroll
    for (int r = 0; r < 4; r++) red[w][quad * 4 + r] = v[r];
  }
  __syncthreads();
#pragma unroll
  for (int r = 0; r < 4; r++) {
    float x = red[0][quad * 4 + r];
#pragma unroll
    for (int ww = 1; ww < 4; ww++) {
      float o = red[ww][quad * 4 + r];
      x = OP ? (x + o) : fmaxf(x, o);
    }
    v[r] = x;
  }
}

// One block = (b, h, 16 q-rows). Scores for both attention maps kept in registers
// (2 x 16 tiles x f32x4 = 128 VGPRs -- ALL indexing must stay compile-time-static,
// otherwise they land in scratch; that was a ~3 GB/launch hidden traffic bug).
// att round-trips LDS (bf16) for the PV A-operand relayout.
// Block swizzle: all 64 q-tiles of one (b,h) share bid%8 -> same XCD -> K/VT slices
// (512 KiB) stay resident in that XCD's 4 MiB L2.
__global__ __launch_bounds__(256, 2) void diff_attn_k(
    const __bf16* __restrict__ Q, const __bf16* __restrict__ Km, const __bf16* __restrict__ VT,
    float* __restrict__ att_out, __bf16* __restrict__ Y, const float* __restrict__ lq1,
    const float* __restrict__ lk1, const float* __restrict__ lq2, const float* __restrict__ lk2,
    const float* __restrict__ rmsw) {
  const int bid = blockIdx.x;
  const int xcd = bid & 7;          // HW round-robins bid%8 across XCDs
  const int rest = bid >> 3;        // 0..1023
  const int qt = rest & 63;
  const int g = (rest >> 6) * 8 + xcd;  // group 0..127, constant per XCD-slot
  const int h = g & 15;
  const int b = g >> 4;
  const int q0 = qt * 16;
  const int tid = threadIdx.x;
  const int lane = tid & 63;
  const int w = tid >> 6;
  const int l15 = lane & 15;
  const int quad = lane >> 4;

  __shared__ __align__(16) __bf16 att_s[16][1032];  // +8 pad: 2064B stride, bank-balanced
  __shared__ float red[4][16];
  __shared__ float s_lam;

  if (tid == 0) {
    float d1 = 0.f, d2 = 0.f;
    for (int i = 0; i < 64; i++) {
      d1 += lq1[i] * lk1[i];
      d2 += lq2[i] * lk2[i];
    }
    s_lam = __expf(d1) - __expf(d2) + 0.2f;  // lambda_full, LAMBDA_INIT=0.2
  }

  // A-frags for q1/q2 (M=16 rows, K=64 as 2 chunks of 32)
  const __bf16* qrow = Q + (long)(b * 1024 + q0 + l15) * 2048 + h * 64 + quad * 8;
  bf16x8 aq1[2], aq2[2];
  aq1[0] = *(const bf16x8*)(qrow);
  aq1[1] = *(const bf16x8*)(qrow + 32);
  aq2[0] = *(const bf16x8*)(qrow + 1024);
  aq2[1] = *(const bf16x8*)(qrow + 1056);

  f32x4 s1[16], s2[16];  // wave w covers key-cols [w*256, w*256+256)
  const __bf16* kb = Km + (long)(b * 1024) * 2048 + h * 64 + quad * 8;
#pragma unroll  // FULL unroll: t must be compile-time so s1/s2 stay in VGPRs
  for (int t = 0; t < 16; t++) {
    const __bf16* kr = kb + (long)(w * 256 + t * 16 + l15) * 2048;
    bf16x8 b10 = *(const bf16x8*)(kr);
    bf16x8 b11 = *(const bf16x8*)(kr + 32);
    bf16x8 b20 = *(const bf16x8*)(kr + 1024);
    bf16x8 b21 = *(const bf16x8*)(kr + 1056);
    f32x4 a = {0.f, 0.f, 0.f, 0.f};
    a = MFMA16(aq1[0], b10, a);
    a = MFMA16(aq1[1], b11, a);
    s1[t] = a;
    f32x4 a2 = {0.f, 0.f, 0.f, 0.f};
    a2 = MFMA16(aq2[0], b20, a2);
    a2 = MFMA16(aq2[1], b21, a2);
    s2[t] = a2;
  }

  const float scale = 0.125f;  // Dh^-0.5
  float m1[4], m2[4];
#pragma unroll
  for (int r = 0; r < 4; r++) {
    float x1 = -3.4e38f, x2 = -3.4e38f;
#pragma unroll
    for (int t = 0; t < 16; t++) {
      x1 = fmaxf(x1, s1[t][r]);
      x2 = fmaxf(x2, s2[t][r]);
    }
    m1[r] = x1;
    m2[r] = x2;
  }
  block_row_reduce<0>(m1, red, w, quad, l15);
  block_row_reduce<0>(m2, red, w, quad, l15);

  float sum1[4] = {0.f, 0.f, 0.f, 0.f}, sum2[4] = {0.f, 0.f, 0.f, 0.f};
#pragma unroll
  for (int t = 0; t < 16; t++) {
#pragma unroll
    for (int r = 0; r < 4; r++) {
      float e1 = __expf((s1[t][r] - m1[r]) * scale);
      float e2 = __expf((s2[t][r] - m2[r]) * scale);
      s1[t][r] = e1;
      s2[t][r] = e2;
      sum1[r] += e1;
      sum2[r] += e2;
    }
  }
  block_row_reduce<1>(sum1, red, w, quad, l15);
  block_row_reduce<1>(sum2, red, w, quad, l15);

  const float lam = s_lam;
  float i1[4], i2[4];
#pragma unroll
  for (int r = 0; r < 4; r++) {
    i1[r] = 1.f / sum1[r];
    i2[r] = lam / sum2[r];
  }

  // Fused att emit: fp32 nontemporal store (output 1) + bf16 LDS tile for PV.
  float* abase = att_out + (long)((b * 16 + h) * 1024 + q0) * 1024;
#pragma unroll
  for (int t = 0; t < 16; t++) {
    int col = w * 256 + t * 16 + l15;
#pragma unroll
    for (int r = 0; r < 4; r++) {
      int row = quad * 4 + r;
      float av = s1[t][r] * i1[r] - s2[t][r] * i2[r];
      __builtin_nontemporal_store(av, abase + (long)row * 1024 + col);
      att_s[row][col] = (__bf16)av;
    }
  }
  __syncthreads();

  // PV: y[16][128] = att[16][1024] @ v[1024][128]; wave w covers d in [w*32, w*32+32)
  f32x4 y0 = {0.f, 0.f, 0.f, 0.f}, y1 = {0.f, 0.f, 0.f, 0.f};
  const __bf16* vb = VT + (long)(b * 2048 + h * 128 + w * 32 + l15) * 1024 + quad * 8;
#pragma unroll 8
  for (int c = 0; c < 32; c++) {
    bf16x8 afr = *(const bf16x8*)(&att_s[l15][c * 32 + quad * 8]);
    bf16x8 b0 = *(const bf16x8*)(vb + c * 32);
    bf16x8 b1 = *(const bf16x8*)(vb + (long)16 * 1024 + c * 32);
    y0 = MFMA16(afr, b0, y0);
    y1 = MFMA16(afr, b1, y1);
  }

  // RMSNorm over d=128 + affine weight + (1 - lambda_init)=0.8
  float ss[4];
#pragma unroll
  for (int r = 0; r < 4; r++) ss[r] = y0[r] * y0[r] + y1[r] * y1[r];
  block_row_reduce<1>(ss, red, w, quad, l15);  // contains barriers: att_s reads done

  const int d0 = w * 32 + l15;
  const float rw0 = rmsw[d0], rw1 = rmsw[d0 + 16];
  // stage Y bf16 in LDS (alias att_s -- free after PV), then 256B-contiguous rows.
  __bf16* ystage = (__bf16*)att_s;  // [16][136] layout
#pragma unroll
  for (int r = 0; r < 4; r++) {
    float rinv = rsqrtf(ss[r] * (1.f / 128.f) + 1e-5f);
    int row = quad * 4 + r;
    ystage[row * 136 + d0] = (__bf16)(y0[r] * rinv * rw0 * 0.8f);
    ystage[row * 136 + d0 + 16] = (__bf16)(y1[r] * rinv * rw1 * 0.8f);
  }
  __syncthreads();
  {
    __bf16* ybase = Y + (long)((b * 16 + h) * 1024 + q0) * 128;
    int row = tid >> 4, c8 = tid & 15;
    bf16x8 v = *(const bf16x8*)(&ystage[row * 136 + c8 * 8]);
    *(bf16x8*)(ybase + row * 128 + c8 * 8) = v;
  }
}

extern "C" void kernel_launch(void* const* d_in, const int* in_sizes, int n_in, void* d_out,
                              int out_size, void* d_ws, size_t ws_size, hipStream_t stream) {
  const float* query = (const float*)d_in[0];
  const float* key = (const float*)d_in[1];
  const float* value = (const float*)d_in[2];
  const float* Wq1 = (const float*)d_in[3];
  const float* Wq2 = (const float*)d_in[4];
  const float* Wk1 = (const float*)d_in[5];
  const float* Wk2 = (const float*)d_in[6];
  const float* Wv = (const float*)d_in[7];
  const float* Wout = (const float*)d_in[8];
  const float* lq1 = (const float*)d_in[9];
  const float* lk1 = (const float*)d_in[10];
  const float* lq2 = (const float*)d_in[11];
  const float* lk2 = (const float*)d_in[12];
  const float* rmsw = (const float*)d_in[13];

  char* ws = (char*)d_ws;
  size_t off = 0;
  auto alloc = [&](size_t bytes) {
    void* p = ws + off;
    off += (bytes + 255) & ~255UL;
    return p;
  };
  const size_t SBE = 8388608;  // 1024*8*1024
  __bf16* qb16 = (__bf16*)alloc(SBE * 2);
  __bf16* kb16 = (__bf16*)alloc(SBE * 2);
  __bf16* vb16 = (__bf16*)alloc(SBE * 2);
  __bf16* wq = (__bf16*)alloc(2097152 * 2);    // [Wq1;Wq2] as [2048][1024]
  __bf16* wk = (__bf16*)alloc(2097152 * 2);
  __bf16* wv = (__bf16*)alloc(2097152 * 2);    // [2048][1024]
  __bf16* wout = (__bf16*)alloc(2097152 * 2);  // [1024][2048]
  __bf16* Qws = (__bf16*)alloc((size_t)8192 * 2048 * 2);
  __bf16* Kws = (__bf16*)alloc((size_t)8192 * 2048 * 2);
  __bf16* VTws = (__bf16*)alloc((size_t)8192 * 2048 * 2);
  __bf16* Yws = (__bf16*)alloc((size_t)8192 * 2048 * 2);

  auto cast = [&](const float* s, __bf16* d, size_t n) {
    int n8 = (int)(n / 8);
    cast_f32_to_bf16_k<<<(n8 + 255) / 256, 256, 0, stream>>>(s, d, n8);
  };
  cast(query, qb16, SBE);
  cast(key, kb16, SBE);
  cast(value, vb16, SBE);
  cast(Wq1, wq, 1048576);
  cast(Wq2, wq + 1048576, 1048576);
  cast(Wk1, wk, 1048576);
  cast(Wk2, wk + 1048576, 1048576);
  cast(Wv, wv, 2097152);
  cast(Wout, wout, 2097152);

  gemm_mfma_k<0><<<dim3(64, 16), 256, 0, stream>>>(qb16, wq, Qws, 1024);
  gemm_mfma_k<0><<<dim3(64, 16), 256, 0, stream>>>(kb16, wk, Kws, 1024);
  gemm_mfma_k<1><<<dim3(64, 16), 256, 0, stream>>>(vb16, wv, VTws, 1024);

  float* att_out = (float*)d_out + SBE;
  diff_attn_k<<<8192, 256, 0, stream>>>(Qws, Kws, VTws, att_out, Yws, lq1, lk1, lq2, lk2, rmsw);

  gemm_mfma_k<2><<<dim3(64, 8), 256, 0, stream>>>(Yws, wout, (float*)d_out, 2048);
}